// Round 7
// baseline (2639.701 us; speedup 1.0000x reference)
//
#include <hip/hip_runtime.h>
#include <hip/hip_bf16.h>
#include <stdint.h>

typedef __bf16 bf16x8 __attribute__((ext_vector_type(8)));
typedef float f32x4 __attribute__((ext_vector_type(4)));
typedef unsigned short ushort_t;
typedef ushort_t ushort8 __attribute__((ext_vector_type(8)));

#define GLDS16(g, l) __builtin_amdgcn_global_load_lds(                          \
    (const __attribute__((address_space(1))) void*)(g),                         \
    (__attribute__((address_space(3))) void*)(l), 16, 0, 0)

__device__ __constant__ float NF4_LUT_C[16] = {
    -1.0f, -0.6961928009986877f, -0.5250730514526367f, -0.39491748809814453f,
    -0.28444138169288635f, -0.18477343022823334f, -0.09105003625154495f, 0.0f,
    0.07958029955625534f, 0.16093020141124725f, 0.24611230194568634f,
    0.33791524171829224f, 0.44070982933044434f, 0.5626170039176941f,
    0.7229568362236023f, 1.0f};

__device__ inline ushort_t f32_to_bf16(float f) {
    uint32_t u = __builtin_bit_cast(uint32_t, f);
    u += 0x7FFFu + ((u >> 16) & 1u);
    return (ushort_t)(u >> 16);
}

// ---------------------------------------------------------------------------
// Kernel 1: cast x (fp32) -> bf16, 8 elems/thread
// ---------------------------------------------------------------------------
__global__ __launch_bounds__(256) void cast_x_kernel(
    const float* __restrict__ x, ushort_t* __restrict__ xb)
{
    const int i = blockIdx.x * 256 + threadIdx.x;
    const float4* p = reinterpret_cast<const float4*>(x);
    float4 a = p[i * 2];
    float4 b = p[i * 2 + 1];
    ushort8 v;
    v[0] = f32_to_bf16(a.x); v[1] = f32_to_bf16(a.y);
    v[2] = f32_to_bf16(a.z); v[3] = f32_to_bf16(a.w);
    v[4] = f32_to_bf16(b.x); v[5] = f32_to_bf16(b.y);
    v[6] = f32_to_bf16(b.z); v[7] = f32_to_bf16(b.w);
    *reinterpret_cast<ushort8*>(xb + (size_t)i * 8) = v;
}

// ---------------------------------------------------------------------------
// Kernel 2: NF4 dequant + transpose -> Wt[n][k] bf16  (unchanged, verified)
// ---------------------------------------------------------------------------
__global__ __launch_bounds__(256) void nf4_dequant_t_kernel(
    const int* __restrict__ q, const float* __restrict__ scales,
    ushort_t* __restrict__ Wt)
{
    __shared__ float lut[16];
    __shared__ ushort_t tile[64][65];
    const int t = threadIdx.x;
    if (t < 16) lut[t] = NF4_LUT_C[t];
    __syncthreads();

    const int nt = blockIdx.x & 63;
    const int kt = blockIdx.x >> 6;

    #pragma unroll
    for (int L = t; L < 512; L += 256) {
        const int r  = L >> 3;
        const int qd = L & 7;
        const int k  = kt * 64 + r;
        const int4 e4 = *reinterpret_cast<const int4*>(q + (size_t)k * 2048 + nt * 32 + qd * 4);
        const float s = scales[k * 64 + nt];
        const int nb = qd * 8;
        int bts[4] = {e4.x, e4.y, e4.z, e4.w};
        #pragma unroll
        for (int e = 0; e < 4; ++e) {
            const int byte = bts[e];
            tile[r][nb + e * 2]     = f32_to_bf16(lut[(byte >> 4) & 0xF] * s);
            tile[r][nb + e * 2 + 1] = f32_to_bf16(lut[byte & 0xF] * s);
        }
    }
    __syncthreads();

    const int nl = t >> 2;
    const int ks = (t & 3) * 16;
    ushort8 v0, v1;
    #pragma unroll
    for (int j = 0; j < 8; ++j) v0[j] = tile[ks + j][nl];
    #pragma unroll
    for (int j = 0; j < 8; ++j) v1[j] = tile[ks + 8 + j][nl];
    ushort_t* dst = Wt + (size_t)(nt * 64 + nl) * 4096 + kt * 64 + ks;
    *reinterpret_cast<ushort8*>(dst)     = v0;
    *reinterpret_cast<ushort8*>(dst + 8) = v1;
}

// ---------------------------------------------------------------------------
// Kernel 3: bf16 GEMM, 256x256 tile, BK=32, 8 waves (2M x 4N), 16x16x32 MFMA.
// r4's proven zero-conflict layout + read pattern, but with a 2-slot ring
// (64 KiB LDS) so TWO blocks fit per CU (4 waves/SIMD): inter-block TLP
// covers barrier/vmcnt stalls (m114 mechanism). Depth-2 prefetch, counted
// vmcnt(4), one barrier pair per K-tile.
// ---------------------------------------------------------------------------
__global__ __launch_bounds__(512, 4) void gemm_nf4_kernel(
    const ushort_t* __restrict__ A, const ushort_t* __restrict__ Bt,
    const float* __restrict__ bias, float* __restrict__ C)
{
    __shared__ __align__(16) ushort_t As[2][256 * 32];
    __shared__ __align__(16) ushort_t Bs[2][256 * 32];

    const int tid  = threadIdx.x;
    const int lane = tid & 63;
    const int wid  = tid >> 6;        // 0..7
    const int wr   = wid >> 2;        // 0..1 -> 128-row A strip
    const int wc   = wid & 3;         // 0..3 -> 64-row B strip
    const int ln15 = lane & 15;
    const int lq   = lane >> 4;       // 0..3 (16B k-slot)

    // XCD-aware bijective swizzle (512 % 8 == 0)
    const int wg  = blockIdx.x;
    const int swz = (wg & 7) * 64 + (wg >> 3);
    const int m0  = (swz >> 4) * 256;   // 32 m-tiles
    const int n0  = (swz & 15) * 256;   // 16 n-tiles

    // staging: LDS row wid*16 + (lane>>2), linear dest; global src k pre-swizzled
    // involution: phys_slot = logical_slot ^ ((row>>1)&3)
    const int srow = wid * 16 + (lane >> 2);
    const int scol = ((lane & 3) ^ ((lane >> 3) & 3)) * 8;
    const ushort_t* gA0 = A  + (size_t)(m0 + srow) * 4096 + scol;
    const ushort_t* gA1 = gA0 + (size_t)128 * 4096;
    const ushort_t* gB0 = Bt + (size_t)(n0 + srow) * 4096 + scol;
    const ushort_t* gB1 = gB0 + (size_t)128 * 4096;
    const int ldsOff0 = (wid * 16) * 32;
    const int ldsOff1 = (128 + wid * 16) * 32;

    f32x4 acc[8][4];
    #pragma unroll
    for (int i = 0; i < 8; ++i)
        #pragma unroll
        for (int j = 0; j < 4; ++j)
            acc[i][j] = (f32x4){0.f, 0.f, 0.f, 0.f};

    // fragment read bases; swizzled k-slot offset is per-lane constant
    const int po  = ((lq ^ ((ln15 >> 1) & 3)) << 3);
    const int rdA = (wr * 128 + ln15) * 32 + po;
    const int rdB = (wc * 64  + ln15) * 32 + po;

    // prologue: stage tiles 0,1 into slots 0,1; wait tile 0
    #pragma unroll
    for (int tt = 0; tt < 2; ++tt) {
        const int kof = tt * 32;
        GLDS16(gA0 + kof, &As[tt][ldsOff0]);
        GLDS16(gA1 + kof, &As[tt][ldsOff1]);
        GLDS16(gB0 + kof, &Bs[tt][ldsOff0]);
        GLDS16(gB1 + kof, &Bs[tt][ldsOff1]);
    }
    asm volatile("s_waitcnt vmcnt(4)" ::: "memory");
    __builtin_amdgcn_s_barrier();
    __builtin_amdgcn_sched_barrier(0);

    for (int t = 0; t < 128; ++t) {
        const int slot = t & 1;
        const ushort_t* Asl = &As[slot][0];
        const ushort_t* Bsl = &Bs[slot][0];
        const int kof = (t + 2) * 32;

        // ---- all fragment reads for this tile (registers) ----
        bf16x8 bf[4], af0[4], af1[4];
        #pragma unroll
        for (int j = 0; j < 4; ++j)
            bf[j] = *reinterpret_cast<const bf16x8*>(Bsl + rdB + j * 16 * 32);
        #pragma unroll
        for (int i = 0; i < 4; ++i)
            af0[i] = *reinterpret_cast<const bf16x8*>(Asl + rdA + i * 16 * 32);
        #pragma unroll
        for (int i = 0; i < 4; ++i)
            af1[i] = *reinterpret_cast<const bf16x8*>(Asl + rdA + (64 + i * 16) * 32);

        // reads complete -> barrier -> safe to re-stage this slot
        asm volatile("s_waitcnt lgkmcnt(0)" ::: "memory");
        __builtin_amdgcn_s_barrier();
        __builtin_amdgcn_sched_barrier(0);
        if (t < 126) {
            GLDS16(gA0 + kof, &As[slot][ldsOff0]);
            GLDS16(gA1 + kof, &As[slot][ldsOff1]);
            GLDS16(gB0 + kof, &Bs[slot][ldsOff0]);
            GLDS16(gB1 + kof, &Bs[slot][ldsOff1]);
        }

        // ---- 32 MFMA on registers, overlapped with the stage above ----
        __builtin_amdgcn_s_setprio(1);
        #pragma unroll
        for (int i = 0; i < 4; ++i)
            #pragma unroll
            for (int j = 0; j < 4; ++j)
                acc[i][j] = __builtin_amdgcn_mfma_f32_16x16x32_bf16(
                    af0[i], bf[j], acc[i][j], 0, 0, 0);
        #pragma unroll
        for (int i = 0; i < 4; ++i)
            #pragma unroll
            for (int j = 0; j < 4; ++j)
                acc[4 + i][j] = __builtin_amdgcn_mfma_f32_16x16x32_bf16(
                    af1[i], bf[j], acc[4 + i][j], 0, 0, 0);
        __builtin_amdgcn_s_setprio(0);

        // ---- tile-boundary: next tile's loads landed? ----
        if (t < 126)       asm volatile("s_waitcnt vmcnt(4)" ::: "memory");
        else if (t == 126) asm volatile("s_waitcnt vmcnt(0)" ::: "memory");
        __builtin_amdgcn_s_barrier();
        __builtin_amdgcn_sched_barrier(0);
    }

    // epilogue: C/D layout col = lane&15, row = (lane>>4)*4 + v
    const int crow0 = m0 + wr * 128 + lq * 4;
    const int ccol0 = n0 + wc * 64 + ln15;
    #pragma unroll
    for (int j = 0; j < 4; ++j) {
        const int c = ccol0 + j * 16;
        const float bv = bias[c];
        #pragma unroll
        for (int i = 0; i < 8; ++i) {
            const int r0 = crow0 + i * 16;
            #pragma unroll
            for (int v = 0; v < 4; ++v)
                C[(size_t)(r0 + v) * 4096 + c] = acc[i][j][v] + bv;
        }
    }
}

// ---------------------------------------------------------------------------
extern "C" void kernel_launch(void* const* d_in, const int* in_sizes, int n_in,
                              void* d_out, int out_size, void* d_ws, size_t ws_size,
                              hipStream_t stream) {
    const float* x      = (const float*)d_in[0];   // [4,2048,4096] fp32
    const int*   q      = (const int*)d_in[1];     // [8388608] byte values
    const float* scales = (const float*)d_in[2];   // [262144]
    const float* bias   = (const float*)d_in[3];   // [4096]
    float* out = (float*)d_out;                    // [8192][4096] fp32

    ushort_t* xb = (ushort_t*)d_ws;                                     // 64 MB bf16 x
    ushort_t* Wt = (ushort_t*)((char*)d_ws + (size_t)64 * 1024 * 1024); // 32 MB bf16 W^T

    cast_x_kernel<<<16384, 256, 0, stream>>>(x, xb);
    nf4_dequant_t_kernel<<<4096, 256, 0, stream>>>(q, scales, Wt);
    gemm_nf4_kernel<<<512, 512, 0, stream>>>(xb, Wt, bias, out);
}

// Round 8
// 440.141 us; speedup vs baseline: 5.9974x; 5.9974x over previous
//
#include <hip/hip_runtime.h>
#include <hip/hip_bf16.h>
#include <stdint.h>

typedef __bf16 bf16x8 __attribute__((ext_vector_type(8)));
typedef float f32x16 __attribute__((ext_vector_type(16)));
typedef unsigned short ushort_t;
typedef ushort_t ushort8 __attribute__((ext_vector_type(8)));

#define GLDS16(g, l) __builtin_amdgcn_global_load_lds(                          \
    (const __attribute__((address_space(1))) void*)(g),                         \
    (__attribute__((address_space(3))) void*)(l), 16, 0, 0)

__device__ __constant__ float NF4_LUT_C[16] = {
    -1.0f, -0.6961928009986877f, -0.5250730514526367f, -0.39491748809814453f,
    -0.28444138169288635f, -0.18477343022823334f, -0.09105003625154495f, 0.0f,
    0.07958029955625534f, 0.16093020141124725f, 0.24611230194568634f,
    0.33791524171829224f, 0.44070982933044434f, 0.5626170039176941f,
    0.7229568362236023f, 1.0f};

__device__ inline ushort_t f32_to_bf16(float f) {
    uint32_t u = __builtin_bit_cast(uint32_t, f);
    u += 0x7FFFu + ((u >> 16) & 1u);
    return (ushort_t)(u >> 16);
}

// ---------------------------------------------------------------------------
// Kernel 1: cast x (fp32) -> bf16, 8 elems/thread
// ---------------------------------------------------------------------------
__global__ __launch_bounds__(256) void cast_x_kernel(
    const float* __restrict__ x, ushort_t* __restrict__ xb)
{
    const int i = blockIdx.x * 256 + threadIdx.x;
    const float4* p = reinterpret_cast<const float4*>(x);
    float4 a = p[i * 2];
    float4 b = p[i * 2 + 1];
    ushort8 v;
    v[0] = f32_to_bf16(a.x); v[1] = f32_to_bf16(a.y);
    v[2] = f32_to_bf16(a.z); v[3] = f32_to_bf16(a.w);
    v[4] = f32_to_bf16(b.x); v[5] = f32_to_bf16(b.y);
    v[6] = f32_to_bf16(b.z); v[7] = f32_to_bf16(b.w);
    *reinterpret_cast<ushort8*>(xb + (size_t)i * 8) = v;
}

// ---------------------------------------------------------------------------
// Kernel 2: NF4 dequant + transpose -> Wt[n][k] bf16  (unchanged, verified)
// ---------------------------------------------------------------------------
__global__ __launch_bounds__(256) void nf4_dequant_t_kernel(
    const int* __restrict__ q, const float* __restrict__ scales,
    ushort_t* __restrict__ Wt)
{
    __shared__ float lut[16];
    __shared__ ushort_t tile[64][65];
    const int t = threadIdx.x;
    if (t < 16) lut[t] = NF4_LUT_C[t];
    __syncthreads();

    const int nt = blockIdx.x & 63;
    const int kt = blockIdx.x >> 6;

    #pragma unroll
    for (int L = t; L < 512; L += 256) {
        const int r  = L >> 3;
        const int qd = L & 7;
        const int k  = kt * 64 + r;
        const int4 e4 = *reinterpret_cast<const int4*>(q + (size_t)k * 2048 + nt * 32 + qd * 4);
        const float s = scales[k * 64 + nt];
        const int nb = qd * 8;
        int bts[4] = {e4.x, e4.y, e4.z, e4.w};
        #pragma unroll
        for (int e = 0; e < 4; ++e) {
            const int byte = bts[e];
            tile[r][nb + e * 2]     = f32_to_bf16(lut[(byte >> 4) & 0xF] * s);
            tile[r][nb + e * 2 + 1] = f32_to_bf16(lut[byte & 0xF] * s);
        }
    }
    __syncthreads();

    const int nl = t >> 2;
    const int ks = (t & 3) * 16;
    ushort8 v0, v1;
    #pragma unroll
    for (int j = 0; j < 8; ++j) v0[j] = tile[ks + j][nl];
    #pragma unroll
    for (int j = 0; j < 8; ++j) v1[j] = tile[ks + 8 + j][nl];
    ushort_t* dst = Wt + (size_t)(nt * 64 + nl) * 4096 + kt * 64 + ks;
    *reinterpret_cast<ushort8*>(dst)     = v0;
    *reinterpret_cast<ushort8*>(dst + 8) = v1;
}

// ---------------------------------------------------------------------------
// Kernel 3: bf16 GEMM, 256x256 tile, BK=64, 8 waves (2M x 4N), 32x32x16 MFMA.
// FRAGMENT-SEQUENTIAL LDS: each (frag-block f, kk) 1KB fragment is stored
// contiguously, so a wave's frag read is base + lane*16B -> perfectly linear,
// ZERO bank conflicts, and all read offsets are compile-time immediates.
// global_load_lds writes linearly (lane*16B); the GLOBAL source address is
// the fragment permutation (row = lane&31, kslot = lane>>5) -> layouts match.
// Double-buffer, stage tile t+1 at top of tile t (into the buffer consumed
// during tile t-1 -> race-free), one vmcnt(0)+barrier per K64-tile with a
// full tile of latency cover. acc/frag layouts refcheck-verified in r6.
// ---------------------------------------------------------------------------
__global__ __launch_bounds__(512, 2) void gemm_nf4_kernel(
    const ushort_t* __restrict__ A, const ushort_t* __restrict__ Bt,
    const float* __restrict__ bias, float* __restrict__ C)
{
    __shared__ __align__(16) ushort_t As[2][16384];   // 2 x 32KB (256 rows x K64)
    __shared__ __align__(16) ushort_t Bs[2][16384];

    const int tid  = threadIdx.x;
    const int lane = tid & 63;
    const int w8   = tid >> 6;       // wave 0..7
    const int wr   = w8 >> 2;        // 0..1 -> 128-row A strip
    const int wc   = w8 & 3;         // 0..3 -> 64-col B strip
    const int ln31 = lane & 31;
    const int lq2  = lane >> 5;      // 0..1

    // XCD-aware bijective swizzle (512 % 8 == 0)
    const int wg  = blockIdx.x;
    const int swz = (wg & 7) * 64 + (wg >> 3);
    const int m0  = (swz >> 4) * 256;   // 32 m-tiles
    const int n0  = (swz & 15) * 256;   // 16 n-tiles

    // staging source: wave w8 owns 32-row block w8; lane -> (row=ln31, k-slot=lq2)
    // issue q (=kk) reads 32B-contig pairs at col q*16
    const ushort_t* gA = A  + (size_t)(m0 + w8 * 32 + ln31) * 4096 + lq2 * 8;
    const ushort_t* gB = Bt + (size_t)(n0 + w8 * 32 + ln31) * 4096 + lq2 * 8;

    f32x16 acc[4][2];
    #pragma unroll
    for (int i = 0; i < 4; ++i)
        #pragma unroll
        for (int j = 0; j < 2; ++j)
            acc[i][j] = (f32x16){0.f};

    // per-lane fragment read bases (ushort offsets); frag (f,kk) at +(f*4+kk)*512
    const int aBase = wr * 8192 + lane * 8;
    const int bBase = wc * 4096 + lane * 8;

    // prologue: stage tile 0 -> buf 0
    #pragma unroll
    for (int q = 0; q < 4; ++q) {
        GLDS16(gA + q * 16, &As[0][(w8 * 4 + q) * 512]);
        GLDS16(gB + q * 16, &Bs[0][(w8 * 4 + q) * 512]);
    }
    asm volatile("s_waitcnt vmcnt(0)" ::: "memory");
    __builtin_amdgcn_s_barrier();
    __builtin_amdgcn_sched_barrier(0);

    for (int t = 0; t < 64; ++t) {
        const int p = t & 1;

        // stage tile t+1 into buf p^1 (fully consumed during tile t-1)
        if (t < 63) {
            const int kof = (t + 1) * 64;
            #pragma unroll
            for (int q = 0; q < 4; ++q) {
                GLDS16(gA + kof + q * 16, &As[p ^ 1][(w8 * 4 + q) * 512]);
                GLDS16(gB + kof + q * 16, &Bs[p ^ 1][(w8 * 4 + q) * 512]);
            }
        }

        const ushort_t* Ab = &As[p][aBase];
        const ushort_t* Bb = &Bs[p][bBase];
        #pragma unroll
        for (int kk = 0; kk < 4; ++kk) {
            bf16x8 af[4], bf[2];
            #pragma unroll
            for (int i = 0; i < 4; ++i)
                af[i] = *reinterpret_cast<const bf16x8*>(Ab + (i * 4 + kk) * 512);
            #pragma unroll
            for (int j = 0; j < 2; ++j)
                bf[j] = *reinterpret_cast<const bf16x8*>(Bb + (j * 4 + kk) * 512);
            __builtin_amdgcn_s_setprio(1);
            #pragma unroll
            for (int i = 0; i < 4; ++i)
                #pragma unroll
                for (int j = 0; j < 2; ++j)
                    acc[i][j] = __builtin_amdgcn_mfma_f32_32x32x16_bf16(
                        af[i], bf[j], acc[i][j], 0, 0, 0);
            __builtin_amdgcn_s_setprio(0);
        }

        if (t < 63) asm volatile("s_waitcnt vmcnt(0)" ::: "memory");
        __builtin_amdgcn_s_barrier();
        __builtin_amdgcn_sched_barrier(0);
    }

    // epilogue: 32x32 C/D layout col = lane&31, row = (reg&3)+8*(reg>>2)+4*lq2
    const int crow_b = m0 + wr * 128 + lq2 * 4;
    const int ccol_b = n0 + wc * 64 + ln31;
    #pragma unroll
    for (int j = 0; j < 2; ++j) {
        const int c = ccol_b + j * 32;
        const float bv = bias[c];
        #pragma unroll
        for (int i = 0; i < 4; ++i) {
            #pragma unroll
            for (int reg = 0; reg < 16; ++reg) {
                const int r = crow_b + i * 32 + (reg & 3) + 8 * (reg >> 2);
                C[(size_t)r * 4096 + c] = acc[i][j][reg] + bv;
            }
        }
    }
}

// ---------------------------------------------------------------------------
extern "C" void kernel_launch(void* const* d_in, const int* in_sizes, int n_in,
                              void* d_out, int out_size, void* d_ws, size_t ws_size,
                              hipStream_t stream) {
    const float* x      = (const float*)d_in[0];   // [4,2048,4096] fp32
    const int*   q      = (const int*)d_in[1];     // [8388608] byte values
    const float* scales = (const float*)d_in[2];   // [262144]
    const float* bias   = (const float*)d_in[3];   // [4096]
    float* out = (float*)d_out;                    // [8192][4096] fp32

    ushort_t* xb = (ushort_t*)d_ws;                                     // 64 MB bf16 x
    ushort_t* Wt = (ushort_t*)((char*)d_ws + (size_t)64 * 1024 * 1024); // 32 MB bf16 W^T

    cast_x_kernel<<<16384, 256, 0, stream>>>(x, xb);
    nf4_dequant_t_kernel<<<4096, 256, 0, stream>>>(q, scales, Wt);
    gemm_nf4_kernel<<<512, 512, 0, stream>>>(xb, Wt, bias, out);
}

// Round 9
// 317.843 us; speedup vs baseline: 8.3050x; 1.3848x over previous
//
#include <hip/hip_runtime.h>
#include <hip/hip_bf16.h>
#include <stdint.h>

typedef __bf16 bf16x8 __attribute__((ext_vector_type(8)));
typedef float f32x16 __attribute__((ext_vector_type(16)));
typedef unsigned short ushort_t;
typedef ushort_t ushort8 __attribute__((ext_vector_type(8)));

#define GLDS16(g, l) __builtin_amdgcn_global_load_lds(                          \
    (const __attribute__((address_space(1))) void*)(g),                         \
    (__attribute__((address_space(3))) void*)(l), 16, 0, 0)

__device__ __constant__ float NF4_LUT_C[16] = {
    -1.0f, -0.6961928009986877f, -0.5250730514526367f, -0.39491748809814453f,
    -0.28444138169288635f, -0.18477343022823334f, -0.09105003625154495f, 0.0f,
    0.07958029955625534f, 0.16093020141124725f, 0.24611230194568634f,
    0.33791524171829224f, 0.44070982933044434f, 0.5626170039176941f,
    0.7229568362236023f, 1.0f};

__device__ inline ushort_t f32_to_bf16(float f) {
    uint32_t u = __builtin_bit_cast(uint32_t, f);
    u += 0x7FFFu + ((u >> 16) & 1u);
    return (ushort_t)(u >> 16);
}

// Packed fragment layout (both operands): chunk (b, kb) = 1KB holding, for
// lane l, elems e 0..7:  value[row = b*32 + (l&31)][k = kb*16 + (l>>5)*8 + e].
// Flat ushort index: (b*256 + kb)*512 + l*8 + e.   (256 kb's per 4096-K row)

// ---------------------------------------------------------------------------
// Kernel 1: cast x (fp32) -> bf16 packed fragments. Block: 32 rows x 128 cols.
// ---------------------------------------------------------------------------
__global__ __launch_bounds__(256) void cast_x_kernel(
    const float* __restrict__ x, ushort_t* __restrict__ A_pk)
{
    __shared__ ushort_t lt[32][130];   // odd dword stride -> conflict-free
    const int t  = threadIdx.x;
    const int mb = blockIdx.x >> 5;    // 0..255 (m-block of 32 rows)
    const int kc = blockIdx.x & 31;    // 0..31  (k-chunk of 128 cols)

    // read: 16 consecutive floats per thread (coalesced), convert, LDS
    {
        const int rl = t >> 3;                 // 0..31
        const int c0 = (t & 7) * 16;           // 0..112
        const float4* p = reinterpret_cast<const float4*>(
            x + (size_t)(mb * 32 + rl) * 4096 + kc * 128 + c0);
        #pragma unroll
        for (int q = 0; q < 4; ++q) {
            float4 a = p[q];
            lt[rl][c0 + q * 4 + 0] = f32_to_bf16(a.x);
            lt[rl][c0 + q * 4 + 1] = f32_to_bf16(a.y);
            lt[rl][c0 + q * 4 + 2] = f32_to_bf16(a.z);
            lt[rl][c0 + q * 4 + 3] = f32_to_bf16(a.w);
        }
    }
    __syncthreads();

    // write: 2 chunks of 16B per thread, fully coalesced 8KB per block
    ushort_t* dst = A_pk + ((size_t)mb * 256 + kc * 8) * 512 + t * 16;
    #pragma unroll
    for (int h = 0; h < 2; ++h) {
        const int c  = 2 * t + h;          // 0..511
        const int kb = c >> 6;             // 0..7 (local)
        const int l  = c & 63;
        const int rl = l & 31;
        const int k0 = kb * 16 + (l >> 5) * 8;
        ushort8 v;
        #pragma unroll
        for (int e = 0; e < 8; ++e) v[e] = lt[rl][k0 + e];
        *reinterpret_cast<ushort8*>(dst + h * 8) = v;
    }
}

// ---------------------------------------------------------------------------
// Kernel 2: NF4 dequant -> packed B fragments (B^T semantics: b-block = n).
// Block: 64 k x 64 n region (as before), then packed-chunk writes.
// ---------------------------------------------------------------------------
__global__ __launch_bounds__(256) void nf4_dequant_t_kernel(
    const int* __restrict__ q, const float* __restrict__ scales,
    ushort_t* __restrict__ B_pk)
{
    __shared__ float lut[16];
    __shared__ ushort_t tile[64][65];   // [k_local][n_local]
    const int t = threadIdx.x;
    if (t < 16) lut[t] = NF4_LUT_C[t];
    __syncthreads();

    const int nt = blockIdx.x & 63;
    const int kt = blockIdx.x >> 6;

    #pragma unroll
    for (int L = t; L < 512; L += 256) {
        const int r  = L >> 3;
        const int qd = L & 7;
        const int k  = kt * 64 + r;
        const int4 e4 = *reinterpret_cast<const int4*>(q + (size_t)k * 2048 + nt * 32 + qd * 4);
        const float s = scales[k * 64 + nt];
        const int nb = qd * 8;
        int bts[4] = {e4.x, e4.y, e4.z, e4.w};
        #pragma unroll
        for (int e = 0; e < 4; ++e) {
            const int byte = bts[e];
            tile[r][nb + e * 2]     = f32_to_bf16(lut[(byte >> 4) & 0xF] * s);
            tile[r][nb + e * 2 + 1] = f32_to_bf16(lut[byte & 0xF] * s);
        }
    }
    __syncthreads();

    // write 2 chunks of 16B per thread. Region: nb_g = nt*2 + nbl, kb_g = kt*4 + kbl
    #pragma unroll
    for (int h = 0; h < 2; ++h) {
        const int c   = 2 * t + h;           // 0..511
        const int nbl = c >> 8;              // 0..1
        const int kbl = (c >> 6) & 3;        // 0..3
        const int l   = c & 63;
        const int nl  = nbl * 32 + (l & 31);
        const int k0  = kbl * 16 + (l >> 5) * 8;
        ushort8 v;
        #pragma unroll
        for (int e = 0; e < 8; ++e) v[e] = tile[k0 + e][nl];
        ushort_t* dst = B_pk + ((size_t)(nt * 2 + nbl) * 256 + kt * 4 + kbl) * 512 + l * 8;
        *reinterpret_cast<ushort8*>(dst) = v;
    }
}

// ---------------------------------------------------------------------------
// Kernel 3: bf16 GEMM, 256x256 tile, BK=64, 8 waves (2M x 4N), 32x32x16 MFMA.
// Operands pre-packed in fragment order -> every staging instruction reads a
// contiguous 1KB chunk (perfect coalescing) and lands linearly in LDS already
// fragment-sequential: frag reads = base + lane*16B + imm (zero conflicts,
// zero VALU address math). Double-buffer, stage t+1 at top of tile t,
// vmcnt(0)+barrier per K64-tile. acc/frag/epilogue layouts r6/r8-verified.
// ---------------------------------------------------------------------------
__global__ __launch_bounds__(512, 2) void gemm_nf4_kernel(
    const ushort_t* __restrict__ A_pk, const ushort_t* __restrict__ B_pk,
    const float* __restrict__ bias, float* __restrict__ C)
{
    __shared__ __align__(16) ushort_t As[2][16384];   // 2 x 32KB
    __shared__ __align__(16) ushort_t Bs[2][16384];

    const int tid  = threadIdx.x;
    const int lane = tid & 63;
    const int w8   = tid >> 6;       // wave 0..7
    const int wr   = w8 >> 2;        // 0..1 -> 128-row A strip
    const int wc   = w8 & 3;         // 0..3 -> 64-col B strip
    const int ln31 = lane & 31;
    const int lq2  = lane >> 5;      // 0..1

    // XCD-aware bijective swizzle (512 % 8 == 0)
    const int wg  = blockIdx.x;
    const int swz = (wg & 7) * 64 + (wg >> 3);
    const int m0  = (swz >> 4) * 256;   // 32 m-tiles
    const int n0  = (swz & 15) * 256;   // 16 n-tiles

    // staging: wave w8 stages block (m0/32 + w8) of A, (n0/32 + w8) of B.
    // Source is contiguous 1KB per chunk; lane supplies +lane*16B.
    const ushort_t* gA = A_pk + ((size_t)(m0 >> 5) + w8) * (256 * 512) + lane * 8;
    const ushort_t* gB = B_pk + ((size_t)(n0 >> 5) + w8) * (256 * 512) + lane * 8;

    f32x16 acc[4][2];
    #pragma unroll
    for (int i = 0; i < 4; ++i)
        #pragma unroll
        for (int j = 0; j < 2; ++j)
            acc[i][j] = (f32x16){0.f};

    // per-lane fragment read bases (ushort offsets); frag (b,kk) at +(b*4+kk)*512
    const int aBase = wr * 8192 + lane * 8;
    const int bBase = wc * 4096 + lane * 8;

    // prologue: stage tile 0 -> buf 0 (kb 0..3)
    #pragma unroll
    for (int qq = 0; qq < 4; ++qq) {
        GLDS16(gA + qq * 512, &As[0][(w8 * 4 + qq) * 512]);
        GLDS16(gB + qq * 512, &Bs[0][(w8 * 4 + qq) * 512]);
    }
    asm volatile("s_waitcnt vmcnt(0)" ::: "memory");
    __builtin_amdgcn_s_barrier();
    __builtin_amdgcn_sched_barrier(0);

    for (int t = 0; t < 64; ++t) {
        const int p = t & 1;

        // stage tile t+1 into buf p^1 (its reads finished before last barrier)
        if (t < 63) {
            const int kof = (t + 1) * 2048;     // 4 chunks of 512
            #pragma unroll
            for (int qq = 0; qq < 4; ++qq) {
                GLDS16(gA + kof + qq * 512, &As[p ^ 1][(w8 * 4 + qq) * 512]);
                GLDS16(gB + kof + qq * 512, &Bs[p ^ 1][(w8 * 4 + qq) * 512]);
            }
        }

        const ushort_t* Ab = &As[p][aBase];
        const ushort_t* Bb = &Bs[p][bBase];
        #pragma unroll
        for (int kk = 0; kk < 4; ++kk) {
            bf16x8 af[4], bf[2];
            #pragma unroll
            for (int i = 0; i < 4; ++i)
                af[i] = *reinterpret_cast<const bf16x8*>(Ab + (i * 4 + kk) * 512);
            #pragma unroll
            for (int j = 0; j < 2; ++j)
                bf[j] = *reinterpret_cast<const bf16x8*>(Bb + (j * 4 + kk) * 512);
            __builtin_amdgcn_s_setprio(1);
            #pragma unroll
            for (int i = 0; i < 4; ++i)
                #pragma unroll
                for (int j = 0; j < 2; ++j)
                    acc[i][j] = __builtin_amdgcn_mfma_f32_32x32x16_bf16(
                        af[i], bf[j], acc[i][j], 0, 0, 0);
            __builtin_amdgcn_s_setprio(0);
        }

        if (t < 63) asm volatile("s_waitcnt vmcnt(0)" ::: "memory");
        __builtin_amdgcn_s_barrier();
        __builtin_amdgcn_sched_barrier(0);
    }

    // epilogue: 32x32 C/D layout col = lane&31, row = (reg&3)+8*(reg>>2)+4*lq2
    const int crow_b = m0 + wr * 128 + lq2 * 4;
    const int ccol_b = n0 + wc * 64 + ln31;
    #pragma unroll
    for (int j = 0; j < 2; ++j) {
        const int c = ccol_b + j * 32;
        const float bv = bias[c];
        #pragma unroll
        for (int i = 0; i < 4; ++i) {
            #pragma unroll
            for (int reg = 0; reg < 16; ++reg) {
                const int r = crow_b + i * 32 + (reg & 3) + 8 * (reg >> 2);
                C[(size_t)r * 4096 + c] = acc[i][j][reg] + bv;
            }
        }
    }
}

// ---------------------------------------------------------------------------
extern "C" void kernel_launch(void* const* d_in, const int* in_sizes, int n_in,
                              void* d_out, int out_size, void* d_ws, size_t ws_size,
                              hipStream_t stream) {
    const float* x      = (const float*)d_in[0];   // [4,2048,4096] fp32
    const int*   q      = (const int*)d_in[1];     // [8388608] byte values
    const float* scales = (const float*)d_in[2];   // [262144]
    const float* bias   = (const float*)d_in[3];   // [4096]
    float* out = (float*)d_out;                    // [8192][4096] fp32

    ushort_t* A_pk = (ushort_t*)d_ws;                                     // 64 MB packed x
    ushort_t* B_pk = (ushort_t*)((char*)d_ws + (size_t)64 * 1024 * 1024); // 32 MB packed W

    cast_x_kernel<<<8192, 256, 0, stream>>>(x, A_pk);
    nf4_dequant_t_kernel<<<4096, 256, 0, stream>>>(q, scales, B_pk);
    gemm_nf4_kernel<<<512, 512, 0, stream>>>(A_pk, B_pk, bias, out);
}

// Round 10
// 303.817 us; speedup vs baseline: 8.6885x; 1.0462x over previous
//
#include <hip/hip_runtime.h>
#include <hip/hip_bf16.h>
#include <stdint.h>

typedef __bf16 bf16x8 __attribute__((ext_vector_type(8)));
typedef float f32x16 __attribute__((ext_vector_type(16)));
typedef unsigned short ushort_t;
typedef ushort_t ushort8 __attribute__((ext_vector_type(8)));

#define GLDS16(g, l) __builtin_amdgcn_global_load_lds(                          \
    (const __attribute__((address_space(1))) void*)(g),                         \
    (__attribute__((address_space(3))) void*)(l), 16, 0, 0)

__device__ __constant__ float NF4_LUT_C[16] = {
    -1.0f, -0.6961928009986877f, -0.5250730514526367f, -0.39491748809814453f,
    -0.28444138169288635f, -0.18477343022823334f, -0.09105003625154495f, 0.0f,
    0.07958029955625534f, 0.16093020141124725f, 0.24611230194568634f,
    0.33791524171829224f, 0.44070982933044434f, 0.5626170039176941f,
    0.7229568362236023f, 1.0f};

__device__ inline ushort_t f32_to_bf16(float f) {
    uint32_t u = __builtin_bit_cast(uint32_t, f);
    u += 0x7FFFu + ((u >> 16) & 1u);
    return (ushort_t)(u >> 16);
}

// Packed fragment layout (both operands): chunk (b, kb) = 1KB holding, for
// lane l, elems e 0..7:  value[row = b*32 + (l&31)][k = kb*16 + (l>>5)*8 + e].
// Flat ushort index: (b*256 + kb)*512 + l*8 + e.   (256 kb's per 4096-K row)

// ---------------------------------------------------------------------------
// Kernel 1: cast x (fp32) -> bf16 packed fragments. Block: 32 rows x 128 cols.
// ---------------------------------------------------------------------------
__global__ __launch_bounds__(256) void cast_x_kernel(
    const float* __restrict__ x, ushort_t* __restrict__ A_pk)
{
    __shared__ ushort_t lt[32][130];
    const int t  = threadIdx.x;
    const int mb = blockIdx.x >> 5;    // 0..255
    const int kc = blockIdx.x & 31;    // 0..31

    {
        const int rl = t >> 3;
        const int c0 = (t & 7) * 16;
        const float4* p = reinterpret_cast<const float4*>(
            x + (size_t)(mb * 32 + rl) * 4096 + kc * 128 + c0);
        #pragma unroll
        for (int q = 0; q < 4; ++q) {
            float4 a = p[q];
            lt[rl][c0 + q * 4 + 0] = f32_to_bf16(a.x);
            lt[rl][c0 + q * 4 + 1] = f32_to_bf16(a.y);
            lt[rl][c0 + q * 4 + 2] = f32_to_bf16(a.z);
            lt[rl][c0 + q * 4 + 3] = f32_to_bf16(a.w);
        }
    }
    __syncthreads();

    ushort_t* dst = A_pk + ((size_t)mb * 256 + kc * 8) * 512 + t * 16;
    #pragma unroll
    for (int h = 0; h < 2; ++h) {
        const int c  = 2 * t + h;
        const int kb = c >> 6;
        const int l  = c & 63;
        const int rl = l & 31;
        const int k0 = kb * 16 + (l >> 5) * 8;
        ushort8 v;
        #pragma unroll
        for (int e = 0; e < 8; ++e) v[e] = lt[rl][k0 + e];
        *reinterpret_cast<ushort8*>(dst + h * 8) = v;
    }
}

// ---------------------------------------------------------------------------
// Kernel 2: NF4 dequant -> packed B fragments (b-block = n, k-contiguous)
// ---------------------------------------------------------------------------
__global__ __launch_bounds__(256) void nf4_dequant_t_kernel(
    const int* __restrict__ q, const float* __restrict__ scales,
    ushort_t* __restrict__ B_pk)
{
    __shared__ float lut[16];
    __shared__ ushort_t tile[64][65];   // [k_local][n_local]
    const int t = threadIdx.x;
    if (t < 16) lut[t] = NF4_LUT_C[t];
    __syncthreads();

    const int nt = blockIdx.x & 63;
    const int kt = blockIdx.x >> 6;

    #pragma unroll
    for (int L = t; L < 512; L += 256) {
        const int r  = L >> 3;
        const int qd = L & 7;
        const int k  = kt * 64 + r;
        const int4 e4 = *reinterpret_cast<const int4*>(q + (size_t)k * 2048 + nt * 32 + qd * 4);
        const float s = scales[k * 64 + nt];
        const int nb = qd * 8;
        int bts[4] = {e4.x, e4.y, e4.z, e4.w};
        #pragma unroll
        for (int e = 0; e < 4; ++e) {
            const int byte = bts[e];
            tile[r][nb + e * 2]     = f32_to_bf16(lut[(byte >> 4) & 0xF] * s);
            tile[r][nb + e * 2 + 1] = f32_to_bf16(lut[byte & 0xF] * s);
        }
    }
    __syncthreads();

    #pragma unroll
    for (int h = 0; h < 2; ++h) {
        const int c   = 2 * t + h;
        const int nbl = c >> 8;
        const int kbl = (c >> 6) & 3;
        const int l   = c & 63;
        const int nl  = nbl * 32 + (l & 31);
        const int k0  = kbl * 16 + (l >> 5) * 8;
        ushort8 v;
        #pragma unroll
        for (int e = 0; e < 8; ++e) v[e] = tile[k0 + e][nl];
        ushort_t* dst = B_pk + ((size_t)(nt * 2 + nbl) * 256 + kt * 4 + kbl) * 512 + l * 8;
        *reinterpret_cast<ushort8*>(dst) = v;
    }
}

// ---------------------------------------------------------------------------
// Kernel 3: bf16 GEMM, 256x256 tile, BK=32, 8 waves (2M x 4N), 32x32x16 MFMA.
// Packed-fragment LDS (r9: zero conflicts, zero VALU addr, coalesced 1KB
// staging chunks) x r4's ring discipline (4 slots, depth-3 prefetch, counted
// vmcnt(8)/4/0, ONE barrier per K32-tile). Per wave per tile: 12 ds_read_b128
// + 4 GLDS16 + 16 MFMA. Ring race-freedom: stage into (t+3)&3 = (t-1)&3,
// whose reads were ordered by the t-1 boundary barrier.
// ---------------------------------------------------------------------------
__global__ __launch_bounds__(512, 2) void gemm_nf4_kernel(
    const ushort_t* __restrict__ A_pk, const ushort_t* __restrict__ B_pk,
    const float* __restrict__ bias, float* __restrict__ C)
{
    // per slot: A 8mb x 2kb x 512 = 16KB, B same -> 32KB; 4 slots = 128KB
    __shared__ __align__(16) ushort_t As[4][8192];
    __shared__ __align__(16) ushort_t Bs[4][8192];

    const int tid  = threadIdx.x;
    const int lane = tid & 63;
    const int w8   = tid >> 6;       // 0..7
    const int wr   = w8 >> 2;        // 0..1 -> 128-row A strip
    const int wc   = w8 & 3;         // 0..3 -> 64-col B strip
    const int ln31 = lane & 31;
    const int lq2  = lane >> 5;      // 0..1

    // XCD-aware bijective swizzle (512 % 8 == 0)
    const int wg  = blockIdx.x;
    const int swz = (wg & 7) * 64 + (wg >> 3);
    const int m0  = (swz >> 4) * 256;   // 32 m-tiles
    const int n0  = (swz & 15) * 256;   // 16 n-tiles

    // staging sources: wave w8 owns m-block (m0/32 + w8) of A and n-block of B;
    // per tile it stages kb 0,1 (1KB contiguous chunks, lane -> +lane*16B)
    const ushort_t* gA = A_pk + ((size_t)(m0 >> 5) + w8) * (256 * 512) + lane * 8;
    const ushort_t* gB = B_pk + ((size_t)(n0 >> 5) + w8) * (256 * 512) + lane * 8;

    f32x16 acc[4][2];
    #pragma unroll
    for (int i = 0; i < 4; ++i)
        #pragma unroll
        for (int j = 0; j < 2; ++j)
            acc[i][j] = (f32x16){0.f};

    // fragment LDS offsets: A frag (i,kk) at wr*4096 + i*1024 + kk*512 + lane*8
    const int aBase = wr * 4096 + lane * 8;
    const int bBase = wc * 2048 + lane * 8;

    // prologue: stage tiles 0,1,2 into slots 0,1,2 (4 loads/wave each)
    #pragma unroll
    for (int tt = 0; tt < 3; ++tt) {
        #pragma unroll
        for (int kb = 0; kb < 2; ++kb) {
            GLDS16(gA + (tt * 2 + kb) * 512, &As[tt][(w8 * 2 + kb) * 512]);
            GLDS16(gB + (tt * 2 + kb) * 512, &Bs[tt][(w8 * 2 + kb) * 512]);
        }
    }
    asm volatile("s_waitcnt vmcnt(8)" ::: "memory");   // tile 0 landed
    __builtin_amdgcn_s_barrier();
    __builtin_amdgcn_sched_barrier(0);

    for (int t = 0; t < 128; ++t) {
        const int slot  = t & 3;
        const int nslot = (t + 3) & 3;
        const ushort_t* Asl = &As[slot][aBase];
        const ushort_t* Bsl = &Bs[slot][bBase];
        const int kof = (t + 3) * 1024;

        // ---- kk = 0: frag reads + stage A chunks of tile t+3 + 8 MFMA ----
        bf16x8 af0[4], bf0[2], af1[4], bf1[2];
        #pragma unroll
        for (int i = 0; i < 4; ++i)
            af0[i] = *reinterpret_cast<const bf16x8*>(Asl + i * 1024);
        #pragma unroll
        for (int j = 0; j < 2; ++j)
            bf0[j] = *reinterpret_cast<const bf16x8*>(Bsl + j * 1024);
        if (t < 125) {
            GLDS16(gA + kof,       &As[nslot][(w8 * 2) * 512]);
            GLDS16(gA + kof + 512, &As[nslot][(w8 * 2 + 1) * 512]);
        }
        __builtin_amdgcn_s_setprio(1);
        #pragma unroll
        for (int i = 0; i < 4; ++i)
            #pragma unroll
            for (int j = 0; j < 2; ++j)
                acc[i][j] = __builtin_amdgcn_mfma_f32_32x32x16_bf16(
                    af0[i], bf0[j], acc[i][j], 0, 0, 0);
        __builtin_amdgcn_s_setprio(0);

        // ---- kk = 1: frag reads + stage B chunks of tile t+3 + 8 MFMA ----
        #pragma unroll
        for (int i = 0; i < 4; ++i)
            af1[i] = *reinterpret_cast<const bf16x8*>(Asl + i * 1024 + 512);
        #pragma unroll
        for (int j = 0; j < 2; ++j)
            bf1[j] = *reinterpret_cast<const bf16x8*>(Bsl + j * 1024 + 512);
        if (t < 125) {
            GLDS16(gB + kof,       &Bs[nslot][(w8 * 2) * 512]);
            GLDS16(gB + kof + 512, &Bs[nslot][(w8 * 2 + 1) * 512]);
        }
        __builtin_amdgcn_s_setprio(1);
        #pragma unroll
        for (int i = 0; i < 4; ++i)
            #pragma unroll
            for (int j = 0; j < 2; ++j)
                acc[i][j] = __builtin_amdgcn_mfma_f32_32x32x16_bf16(
                    af1[i], bf1[j], acc[i][j], 0, 0, 0);
        __builtin_amdgcn_s_setprio(0);

        // ---- tile boundary: own prefetch counted, one barrier ----
        if (t < 125)       asm volatile("s_waitcnt vmcnt(8)" ::: "memory");
        else if (t == 125) asm volatile("s_waitcnt vmcnt(4)" ::: "memory");
        else if (t == 126) asm volatile("s_waitcnt vmcnt(0)" ::: "memory");
        __builtin_amdgcn_s_barrier();
        __builtin_amdgcn_sched_barrier(0);
    }

    // epilogue: 32x32 C/D layout col = lane&31, row = (reg&3)+8*(reg>>2)+4*lq2
    const int crow_b = m0 + wr * 128 + lq2 * 4;
    const int ccol_b = n0 + wc * 64 + ln31;
    #pragma unroll
    for (int j = 0; j < 2; ++j) {
        const int c = ccol_b + j * 32;
        const float bv = bias[c];
        #pragma unroll
        for (int i = 0; i < 4; ++i) {
            #pragma unroll
            for (int reg = 0; reg < 16; ++reg) {
                const int r = crow_b + i * 32 + (reg & 3) + 8 * (reg >> 2);
                C[(size_t)r * 4096 + c] = acc[i][j][reg] + bv;
            }
        }
    }
}

// ---------------------------------------------------------------------------
extern "C" void kernel_launch(void* const* d_in, const int* in_sizes, int n_in,
                              void* d_out, int out_size, void* d_ws, size_t ws_size,
                              hipStream_t stream) {
    const float* x      = (const float*)d_in[0];   // [4,2048,4096] fp32
    const int*   q      = (const int*)d_in[1];     // [8388608] byte values
    const float* scales = (const float*)d_in[2];   // [262144]
    const float* bias   = (const float*)d_in[3];   // [4096]
    float* out = (float*)d_out;                    // [8192][4096] fp32

    ushort_t* A_pk = (ushort_t*)d_ws;                                     // 64 MB packed x
    ushort_t* B_pk = (ushort_t*)((char*)d_ws + (size_t)64 * 1024 * 1024); // 32 MB packed W

    cast_x_kernel<<<8192, 256, 0, stream>>>(x, A_pk);
    nf4_dequant_t_kernel<<<4096, 256, 0, stream>>>(q, scales, B_pk);
    gemm_nf4_kernel<<<512, 512, 0, stream>>>(A_pk, B_pk, bias, out);
}